// Round 1
// baseline (311.009 us; speedup 1.0000x reference)
//
#include <hip/hip_runtime.h>

#pragma clang fp contract(off)

#define B_     512
#define N_     16384
#define A_     64
#define TPB    1024
#define CAP    2048
#define NCHUNK 16            // N_ / TPB
#define NBUF   3             // triple-buffered staging

#define AS1 __attribute__((address_space(1)))
#define AS3 __attribute__((address_space(3)))

// async global->LDS, 16 B per lane, no VGPR round-trip (HW: wave-uniform LDS
// base + lane*16; we pass per-lane ptr, firstlane value is the base).
__device__ __forceinline__ void gl2lds16(const float* g, float* l) {
    __builtin_amdgcn_global_load_lds((const AS1 unsigned int*)g,
                                     (AS3 unsigned int*)l, 16, 0, 0);
}

// One block per batch: centroid (bit-exact numpy order) + distances +
// exact top-k select (16-bit radix + boundary rank) + both mask writes.
// Phase A streams pos/mask through LDS via global_load_lds (3-deep pipeline,
// counted vmcnt) so memory parallelism is not VGPR-limited.
__global__ __launch_bounds__(TPB, 8) void fused_kernel(
    const float* __restrict__ pos,   const float* __restrict__ mask,
    const float* __restrict__ apos,  const float* __restrict__ amask,
    const int*   __restrict__ topk_ptr,
    float* __restrict__ out0, float* __restrict__ out1)
{
#pragma clang fp contract(off)
    __shared__ __align__(16) float stage[NBUF][4096]; // 48 KB: 12KB pos + 4KB mask per chunk
    __shared__ unsigned       hist[2048];             // 8 KB: 11-bit prefix histogram
    __shared__ unsigned       hist2[32];              // 5-bit refinement
    __shared__ unsigned       cand_bits[CAP];         // boundary candidates
    __shared__ unsigned short cand_idx[CAP];
    __shared__ unsigned char  sel_flags[CAP];         // rank<j per candidate
    __shared__ float          s_atoms[A_ * 3 + A_];   // 192 pos + 64 mask
    __shared__ float          s_c[3];
    __shared__ unsigned s_B11, s_less11, s_P16, s_j, s_ncand, s_k;

    const int tid = threadIdx.x;
    const int b   = blockIdx.x;
    const float* __restrict__ p = pos  + (size_t)b * N_ * 3;
    const float* __restrict__ m = mask + (size_t)b * N_;

    // ---- init: zero hists, stage atoms coalesced, load k ------------------
    hist[tid]        = 0u;
    hist[tid + 1024] = 0u;
    if (tid < 32) hist2[tid] = 0u;
    if (tid < 256)
        s_atoms[tid] = (tid < 192) ? apos[(size_t)b * 192 + tid]
                                   : amask[(size_t)b * 64 + (tid - 192)];
    if (tid == 0) {
        s_ncand = 0u;
        int kk = *topk_ptr;
        if (kk < 0)  kk = 0;
        if (kk > N_) kk = N_;
        s_k = (unsigned)kk;
    }

    // ---- issue chunks 0..2 now; they fly while the centroid runs ----------
    {
        const float* g0 = (tid < 768) ? (p + tid * 4)            : (m + (tid - 768) * 4);
        const float* g1 = (tid < 768) ? (p + 3072 + tid * 4)     : (m + 1024 + (tid - 768) * 4);
        const float* g2 = (tid < 768) ? (p + 2 * 3072 + tid * 4) : (m + 2 * 1024 + (tid - 768) * 4);
        gl2lds16(g0, &stage[0][tid * 4]);
        gl2lds16(g1, &stage[1][tid * 4]);
        gl2lds16(g2, &stage[2][tid * 4]);
    }
    __syncthreads();

    // ---- centroid: lanes 0..2 = component sums (numpy sequential axis=-2),
    //      lane 3 = mask pairwise-8 sum (numpy pairwise for n=64) ----------
    if (tid < 64) {
        float comp = 0.0f, ms = 0.0f;
        if (tid < 3) {
            comp = s_atoms[tid];
            for (int a = 1; a < A_; ++a) comp += s_atoms[a * 3 + tid];
        }
        if (tid == 3) {
            const float* am = s_atoms + 192;
            float r0 = am[0], r1 = am[1], r2 = am[2], r3 = am[3];
            float r4 = am[4], r5 = am[5], r6 = am[6], r7 = am[7];
            for (int i = 8; i < A_; i += 8) {
                r0 += am[i + 0]; r1 += am[i + 1]; r2 += am[i + 2]; r3 += am[i + 3];
                r4 += am[i + 4]; r5 += am[i + 5]; r6 += am[i + 6]; r7 += am[i + 7];
            }
            ms = ((r0 + r1) + (r2 + r3)) + ((r4 + r5) + (r6 + r7));
        }
        ms = __shfl(ms, 3, 64);
        if (tid < 3) s_c[tid] = comp / ms;   // correctly-rounded fp32 divide
    }
    __syncthreads();

    const float cx = s_c[0], cy = s_c[1], cz = s_c[2];
    const unsigned k = s_k;

    // ---- Phase A: streamed distances (bit-exact). elem = c*1024 + tid -----
    unsigned rbits[NCHUNK];
    float    rm[NCHUNK];

#pragma unroll
    for (int c = 0; c < NCHUNK; ++c) {
        // chunk c done when at most the (<=2) newer chunks are outstanding
        if (c <= NCHUNK - 3)      asm volatile("s_waitcnt vmcnt(2)" ::: "memory");
        else if (c == NCHUNK - 2) asm volatile("s_waitcnt vmcnt(1)" ::: "memory");
        else                      asm volatile("s_waitcnt vmcnt(0)" ::: "memory");
        __builtin_amdgcn_s_barrier();
        asm volatile("" ::: "memory");          // reads must stay below barrier

        const float* buf = stage[c % NBUF];
        const float px = buf[3 * tid];          // 2-way bank alias: free
        const float py = buf[3 * tid + 1];
        const float pz = buf[3 * tid + 2];
        const float mm = buf[3072 + tid];

        float dx = cx - px, dy = cy - py, dz = cz - pz;
        float dx2 = dx * dx, dy2 = dy * dy, dz2 = dz * dz;
        float s = (dx2 + dy2) + dz2;            // numpy sum order (no FMA)
        s = s + 1e-12f;
        float d = sqrtf(s);                     // correctly rounded
        d = d + (1.0f - mm) * 1e10f;
        const unsigned bits = __float_as_uint(d);   // monotone, d >= 0
        rbits[c] = bits;
        rm[c]    = mm;
        atomicAdd(&hist[bits >> 21], 1u);

        asm volatile("s_waitcnt lgkmcnt(0)" ::: "memory");  // my reads complete
        __builtin_amdgcn_s_barrier();           // everyone done with this buffer
        asm volatile("" ::: "memory");
        if (c + NBUF < NCHUNK) {                // refill the buffer just freed
            const float* g = (tid < 768)
                ? (p + (size_t)(c + NBUF) * 3072 + tid * 4)
                : (m + (size_t)(c + NBUF) * 1024 + (tid - 768) * 4);
            gl2lds16(g, &stage[c % NBUF][tid * 4]);
        }
    }
    __syncthreads();

    if (k > 0) {
        // ---- Phase B: wave-0 shuffle scan finds the 11-bit bucket ---------
        if (tid < 64) {
            unsigned s = 0;
#pragma unroll
            for (int i = 0; i < 32; ++i) s += hist[tid * 32 + i];
            unsigned incl = s;
#pragma unroll
            for (int off = 1; off < 64; off <<= 1) {
                unsigned v = (unsigned)__shfl_up((int)incl, off, 64);
                if (tid >= off) incl += v;
            }
            unsigned long long bal = __ballot(incl >= k);
            const int g = __ffsll(bal) - 1;
            const unsigned cum1 = (unsigned)__shfl((int)(incl - s), g, 64);

            unsigned h2 = (tid < 32) ? hist[g * 32 + tid] : 0u;
            unsigned incl2 = h2;
#pragma unroll
            for (int off = 1; off < 64; off <<= 1) {
                unsigned v = (unsigned)__shfl_up((int)incl2, off, 64);
                if (tid >= off) incl2 += v;
            }
            unsigned long long bal2 = __ballot(tid < 32 && (cum1 + incl2 >= k));
            const int sb = __ffsll(bal2) - 1;
            const unsigned cum2 = cum1 + (unsigned)__shfl((int)(incl2 - h2), sb, 64);
            if (tid == 0) { s_B11 = (unsigned)(g * 32 + sb); s_less11 = cum2; }
        }
        __syncthreads();
        const unsigned B11 = s_B11;

        // ---- Phase C: refine low-5 bits (from registers, no re-read) ------
#pragma unroll
        for (int x = 0; x < NCHUNK; ++x) {
            const unsigned v = rbits[x] >> 16;
            if ((v >> 5) == B11) atomicAdd(&hist2[v & 31u], 1u);
        }
        __syncthreads();
        if (tid < 64) {
            unsigned h = (tid < 32) ? hist2[tid] : 0u;
            unsigned incl = h;
#pragma unroll
            for (int off = 1; off < 64; off <<= 1) {
                unsigned v = (unsigned)__shfl_up((int)incl, off, 64);
                if (tid >= off) incl += v;
            }
            const unsigned less11 = s_less11;
            unsigned long long bal = __ballot(tid < 32 && (less11 + incl >= k));
            const int sb = __ffsll(bal) - 1;
            const unsigned cumx = less11 + (unsigned)__shfl((int)(incl - h), sb, 64);
            if (tid == 0) { s_P16 = (B11 << 5) | (unsigned)sb; s_j = k - cumx; }
        }
        __syncthreads();
        const unsigned P16 = s_P16;
        const unsigned j   = s_j;

        // ---- Phase D: gather boundary candidates; mark slot in-register ---
        // bits16 can never be 0xFFFF (d >= 0 finite), so it's a safe marker.
#pragma unroll
        for (int c2 = 0; c2 < NCHUNK; ++c2) {
            const unsigned bits = rbits[c2];
            if ((bits >> 16) == P16) {
                const unsigned w = atomicAdd(&s_ncand, 1u);
                if (w < CAP) {
                    cand_bits[w] = bits;
                    cand_idx[w]  = (unsigned short)(c2 * 1024 + tid);
                    rbits[c2] = 0xFFFF0000u | w;
                }
            }
        }
        __syncthreads();

        // ---- Phase E: rank candidates (tie -> lowest index) -> flags ------
        const unsigned cnum = min(s_ncand, (unsigned)CAP);
        for (unsigned t = tid; t < cnum; t += TPB) {
            const unsigned bt = cand_bits[t];
            const unsigned it = cand_idx[t];
            unsigned rank = 0;
            for (unsigned u = 0; u < cnum; ++u) {
                const unsigned bu = cand_bits[u];
                rank += (bu < bt) || (bu == bt && (unsigned)cand_idx[u] < it);
            }
            sel_flags[t] = (rank < j) ? (unsigned char)1 : (unsigned char)0;
        }
        __syncthreads();
    }

    // ---- Phase F: write both masks (everything from registers + flags) ----
    const unsigned P16f = (k > 0) ? s_P16 : 0u;
#pragma unroll
    for (int c2 = 0; c2 < NCHUNK; ++c2) {
        const unsigned v   = rbits[c2];
        const unsigned v16 = v >> 16;
        bool sel = false;
        if (k > 0) {
            sel = (v16 == 0xFFFFu) ? (sel_flags[v & (CAP - 1u)] != 0)
                                   : (v16 < P16f);
        }
        const float mv = rm[c2];
        const size_t o = (size_t)b * N_ + (size_t)c2 * 1024 + tid;
        out0[o] = sel ? 0.0f  : mv;
        out1[o] = sel ? 32.0f : (1.0f - mv);
    }
}

extern "C" void kernel_launch(void* const* d_in, const int* in_sizes, int n_in,
                              void* d_out, int out_size, void* d_ws, size_t ws_size,
                              hipStream_t stream) {
    const float* pos   = (const float*)d_in[0];   // [B,N,3]
    const float* rmask = (const float*)d_in[1];   // [B,N]
    const float* apos  = (const float*)d_in[2];   // [B,A,3]
    const float* amask = (const float*)d_in[3];   // [B,A]
    // d_in[4] = max_p (unused by the reference outputs)
    const int*   topk  = (const int*)d_in[5];

    float* out0 = (float*)d_out;
    float* out1 = out0 + (size_t)B_ * N_;

    fused_kernel<<<B_, TPB, 0, stream>>>(pos, rmask, apos, amask, topk, out0, out1);
}

// Round 2
// 211.611 us; speedup vs baseline: 1.4697x; 1.4697x over previous
//
#include <hip/hip_runtime.h>

#pragma clang fp contract(off)

#define B_     512
#define N_     16384
#define A_     64
#define TPB    1024
#define CAP    2048
#define NCHUNK 16            // N_ / TPB
#define NBUF   3             // triple-buffered staging

#define AS1 __attribute__((address_space(1)))
#define AS3 __attribute__((address_space(3)))

// async global->LDS, 16 B per lane, no VGPR round-trip (HW: wave-uniform LDS
// base + lane*16; we pass per-lane ptr, firstlane value is the base).
__device__ __forceinline__ void gl2lds16(const float* g, float* l) {
    __builtin_amdgcn_global_load_lds((const AS1 unsigned int*)g,
                                     (AS3 unsigned int*)l, 16, 0, 0);
}

// One block per batch: centroid (bit-exact numpy order) + distances +
// exact top-k select (16-bit radix + boundary rank) + both mask writes.
// Phase A streams pos/mask through LDS via global_load_lds (3-deep pipeline,
// counted vmcnt) so memory parallelism is not VGPR-limited.
// NOTE: no min-waves in launch_bounds — (TPB,8) capped VGPRs at 32 and
// spilled rbits[]/rm[] to scratch (+180 MB HBM traffic, round 1 regression).
// LDS (73 KB) already limits to 2 blocks/CU = 32 waves/CU.
__global__ __launch_bounds__(TPB) void fused_kernel(
    const float* __restrict__ pos,   const float* __restrict__ mask,
    const float* __restrict__ apos,  const float* __restrict__ amask,
    const int*   __restrict__ topk_ptr,
    float* __restrict__ out0, float* __restrict__ out1)
{
#pragma clang fp contract(off)
    __shared__ __align__(16) float stage[NBUF][4096]; // 48 KB: 12KB pos + 4KB mask per chunk
    __shared__ unsigned       hist[2048];             // 8 KB: 11-bit prefix histogram
    __shared__ unsigned       hist2[32];              // 5-bit refinement
    __shared__ unsigned       cand_bits[CAP];         // boundary candidates
    __shared__ unsigned short cand_idx[CAP];
    __shared__ unsigned char  sel_flags[CAP];         // rank<j per candidate
    __shared__ float          s_atoms[A_ * 3 + A_];   // 192 pos + 64 mask
    __shared__ float          s_c[3];
    __shared__ unsigned s_B11, s_less11, s_P16, s_j, s_ncand, s_k;

    const int tid = threadIdx.x;
    const int b   = blockIdx.x;
    const float* __restrict__ p = pos  + (size_t)b * N_ * 3;
    const float* __restrict__ m = mask + (size_t)b * N_;

    // ---- init: zero hists, stage atoms coalesced, load k ------------------
    hist[tid]        = 0u;
    hist[tid + 1024] = 0u;
    if (tid < 32) hist2[tid] = 0u;
    if (tid < 256)
        s_atoms[tid] = (tid < 192) ? apos[(size_t)b * 192 + tid]
                                   : amask[(size_t)b * 64 + (tid - 192)];
    if (tid == 0) {
        s_ncand = 0u;
        int kk = *topk_ptr;
        if (kk < 0)  kk = 0;
        if (kk > N_) kk = N_;
        s_k = (unsigned)kk;
    }

    // ---- issue chunks 0..2 now; they fly while the centroid runs ----------
    {
        const float* g0 = (tid < 768) ? (p + tid * 4)            : (m + (tid - 768) * 4);
        const float* g1 = (tid < 768) ? (p + 3072 + tid * 4)     : (m + 1024 + (tid - 768) * 4);
        const float* g2 = (tid < 768) ? (p + 2 * 3072 + tid * 4) : (m + 2 * 1024 + (tid - 768) * 4);
        gl2lds16(g0, &stage[0][tid * 4]);
        gl2lds16(g1, &stage[1][tid * 4]);
        gl2lds16(g2, &stage[2][tid * 4]);
    }
    __syncthreads();

    // ---- centroid: lanes 0..2 = component sums (numpy sequential axis=-2),
    //      lane 3 = mask pairwise-8 sum (numpy pairwise for n=64) ----------
    if (tid < 64) {
        float comp = 0.0f, ms = 0.0f;
        if (tid < 3) {
            comp = s_atoms[tid];
            for (int a = 1; a < A_; ++a) comp += s_atoms[a * 3 + tid];
        }
        if (tid == 3) {
            const float* am = s_atoms + 192;
            float r0 = am[0], r1 = am[1], r2 = am[2], r3 = am[3];
            float r4 = am[4], r5 = am[5], r6 = am[6], r7 = am[7];
            for (int i = 8; i < A_; i += 8) {
                r0 += am[i + 0]; r1 += am[i + 1]; r2 += am[i + 2]; r3 += am[i + 3];
                r4 += am[i + 4]; r5 += am[i + 5]; r6 += am[i + 6]; r7 += am[i + 7];
            }
            ms = ((r0 + r1) + (r2 + r3)) + ((r4 + r5) + (r6 + r7));
        }
        ms = __shfl(ms, 3, 64);
        if (tid < 3) s_c[tid] = comp / ms;   // correctly-rounded fp32 divide
    }
    __syncthreads();

    const float cx = s_c[0], cy = s_c[1], cz = s_c[2];
    const unsigned k = s_k;

    // ---- Phase A: streamed distances (bit-exact). elem = c*1024 + tid -----
    unsigned rbits[NCHUNK];
    float    rm[NCHUNK];

#pragma unroll
    for (int c = 0; c < NCHUNK; ++c) {
        // chunk c done when at most the (<=2) newer chunks are outstanding
        if (c <= NCHUNK - 3)      asm volatile("s_waitcnt vmcnt(2)" ::: "memory");
        else if (c == NCHUNK - 2) asm volatile("s_waitcnt vmcnt(1)" ::: "memory");
        else                      asm volatile("s_waitcnt vmcnt(0)" ::: "memory");
        __builtin_amdgcn_s_barrier();
        asm volatile("" ::: "memory");          // reads must stay below barrier

        const float* buf = stage[c % NBUF];
        const float px = buf[3 * tid];          // 2-way bank alias: free
        const float py = buf[3 * tid + 1];
        const float pz = buf[3 * tid + 2];
        const float mm = buf[3072 + tid];

        float dx = cx - px, dy = cy - py, dz = cz - pz;
        float dx2 = dx * dx, dy2 = dy * dy, dz2 = dz * dz;
        float s = (dx2 + dy2) + dz2;            // numpy sum order (no FMA)
        s = s + 1e-12f;
        float d = sqrtf(s);                     // correctly rounded
        d = d + (1.0f - mm) * 1e10f;
        const unsigned bits = __float_as_uint(d);   // monotone, d >= 0
        rbits[c] = bits;
        rm[c]    = mm;
        atomicAdd(&hist[bits >> 21], 1u);

        asm volatile("s_waitcnt lgkmcnt(0)" ::: "memory");  // my reads complete
        __builtin_amdgcn_s_barrier();           // everyone done with this buffer
        asm volatile("" ::: "memory");
        if (c + NBUF < NCHUNK) {                // refill the buffer just freed
            const float* g = (tid < 768)
                ? (p + (size_t)(c + NBUF) * 3072 + tid * 4)
                : (m + (size_t)(c + NBUF) * 1024 + (tid - 768) * 4);
            gl2lds16(g, &stage[c % NBUF][tid * 4]);
        }
    }
    __syncthreads();

    if (k > 0) {
        // ---- Phase B: wave-0 shuffle scan finds the 11-bit bucket ---------
        if (tid < 64) {
            unsigned s = 0;
#pragma unroll
            for (int i = 0; i < 32; ++i) s += hist[tid * 32 + i];
            unsigned incl = s;
#pragma unroll
            for (int off = 1; off < 64; off <<= 1) {
                unsigned v = (unsigned)__shfl_up((int)incl, off, 64);
                if (tid >= off) incl += v;
            }
            unsigned long long bal = __ballot(incl >= k);
            const int g = __ffsll(bal) - 1;
            const unsigned cum1 = (unsigned)__shfl((int)(incl - s), g, 64);

            unsigned h2 = (tid < 32) ? hist[g * 32 + tid] : 0u;
            unsigned incl2 = h2;
#pragma unroll
            for (int off = 1; off < 64; off <<= 1) {
                unsigned v = (unsigned)__shfl_up((int)incl2, off, 64);
                if (tid >= off) incl2 += v;
            }
            unsigned long long bal2 = __ballot(tid < 32 && (cum1 + incl2 >= k));
            const int sb = __ffsll(bal2) - 1;
            const unsigned cum2 = cum1 + (unsigned)__shfl((int)(incl2 - h2), sb, 64);
            if (tid == 0) { s_B11 = (unsigned)(g * 32 + sb); s_less11 = cum2; }
        }
        __syncthreads();
        const unsigned B11 = s_B11;

        // ---- Phase C: refine low-5 bits (from registers, no re-read) ------
#pragma unroll
        for (int x = 0; x < NCHUNK; ++x) {
            const unsigned v = rbits[x] >> 16;
            if ((v >> 5) == B11) atomicAdd(&hist2[v & 31u], 1u);
        }
        __syncthreads();
        if (tid < 64) {
            unsigned h = (tid < 32) ? hist2[tid] : 0u;
            unsigned incl = h;
#pragma unroll
            for (int off = 1; off < 64; off <<= 1) {
                unsigned v = (unsigned)__shfl_up((int)incl, off, 64);
                if (tid >= off) incl += v;
            }
            const unsigned less11 = s_less11;
            unsigned long long bal = __ballot(tid < 32 && (less11 + incl >= k));
            const int sb = __ffsll(bal) - 1;
            const unsigned cumx = less11 + (unsigned)__shfl((int)(incl - h), sb, 64);
            if (tid == 0) { s_P16 = (B11 << 5) | (unsigned)sb; s_j = k - cumx; }
        }
        __syncthreads();
        const unsigned P16 = s_P16;
        const unsigned j   = s_j;

        // ---- Phase D: gather boundary candidates; mark slot in-register ---
        // bits16 can never be 0xFFFF (d >= 0 finite), so it's a safe marker.
#pragma unroll
        for (int c2 = 0; c2 < NCHUNK; ++c2) {
            const unsigned bits = rbits[c2];
            if ((bits >> 16) == P16) {
                const unsigned w = atomicAdd(&s_ncand, 1u);
                if (w < CAP) {
                    cand_bits[w] = bits;
                    cand_idx[w]  = (unsigned short)(c2 * 1024 + tid);
                    rbits[c2] = 0xFFFF0000u | w;
                }
            }
        }
        __syncthreads();

        // ---- Phase E: rank candidates (tie -> lowest index) -> flags ------
        const unsigned cnum = min(s_ncand, (unsigned)CAP);
        for (unsigned t = tid; t < cnum; t += TPB) {
            const unsigned bt = cand_bits[t];
            const unsigned it = cand_idx[t];
            unsigned rank = 0;
            for (unsigned u = 0; u < cnum; ++u) {
                const unsigned bu = cand_bits[u];
                rank += (bu < bt) || (bu == bt && (unsigned)cand_idx[u] < it);
            }
            sel_flags[t] = (rank < j) ? (unsigned char)1 : (unsigned char)0;
        }
        __syncthreads();
    }

    // ---- Phase F: write both masks (everything from registers + flags) ----
    const unsigned P16f = (k > 0) ? s_P16 : 0u;
#pragma unroll
    for (int c2 = 0; c2 < NCHUNK; ++c2) {
        const unsigned v   = rbits[c2];
        const unsigned v16 = v >> 16;
        bool sel = false;
        if (k > 0) {
            sel = (v16 == 0xFFFFu) ? (sel_flags[v & (CAP - 1u)] != 0)
                                   : (v16 < P16f);
        }
        const float mv = rm[c2];
        const size_t o = (size_t)b * N_ + (size_t)c2 * 1024 + tid;
        out0[o] = sel ? 0.0f  : mv;
        out1[o] = sel ? 32.0f : (1.0f - mv);
    }
}

extern "C" void kernel_launch(void* const* d_in, const int* in_sizes, int n_in,
                              void* d_out, int out_size, void* d_ws, size_t ws_size,
                              hipStream_t stream) {
    const float* pos   = (const float*)d_in[0];   // [B,N,3]
    const float* rmask = (const float*)d_in[1];   // [B,N]
    const float* apos  = (const float*)d_in[2];   // [B,A,3]
    const float* amask = (const float*)d_in[3];   // [B,A]
    // d_in[4] = max_p (unused by the reference outputs)
    const int*   topk  = (const int*)d_in[5];

    float* out0 = (float*)d_out;
    float* out1 = out0 + (size_t)B_ * N_;

    fused_kernel<<<B_, TPB, 0, stream>>>(pos, rmask, apos, amask, topk, out0, out1);
}